// Round 1
// baseline (799.149 us; speedup 1.0000x reference)
//
#include <hip/hip_runtime.h>
#include <stdint.h>

#define DIM 256
#define TOPK 64
#define HIST_BINS 65536
#define CAP 4096

// Monotone float->uint mapping: a > b  <=>  fkey(a) > fkey(b)
__device__ __forceinline__ uint32_t fkey(float f) {
  uint32_t u = __float_as_uint(f);
  return (u & 0x80000000u) ? ~u : (u | 0x80000000u);
}

// Kernel S: one wave per row. lane l holds float4 of columns [4l, 4l+3].
// Also zeroes the histogram + counter (consumed only by later launches).
__global__ __launch_bounds__(256) void score_kernel(
    const float* __restrict__ mat, const float* __restrict__ query,
    float* __restrict__ scores, uint32_t* __restrict__ hist,
    int* __restrict__ cnt, int n) {
  int tid = blockIdx.x * 256 + threadIdx.x;
  if (tid < HIST_BINS) hist[tid] = 0u;
  if (tid == 0) *cnt = 0;

  int wave = tid >> 6;
  int lane = threadIdx.x & 63;
  if (wave < n) {
    float4 q = ((const float4*)query)[lane];
    float4 m = ((const float4*)(mat + (size_t)wave * DIM))[lane];
    float d = m.x * q.x + m.y * q.y + m.z * q.z + m.w * q.w;
#pragma unroll
    for (int off = 32; off > 0; off >>= 1) d += __shfl_xor(d, off, 64);
    if (lane == 0) scores[wave] = d;
  }
}

// Kernel H: 65536-bin histogram of top-16 key bits.
__global__ __launch_bounds__(256) void hist_kernel(
    const float* __restrict__ scores, uint32_t* __restrict__ hist, int n) {
  int i = blockIdx.x * 256 + threadIdx.x;
  int stride = gridDim.x * 256;
  for (; i < n; i += stride) {
    atomicAdd(&hist[fkey(scores[i]) >> 16], 1u);
  }
}

// Kernel T: single block. Find smallest bin t such that
// (# scores with bin >= t) >= TOPK.  Two-level suffix scan.
__global__ __launch_bounds__(256) void thresh_kernel(
    const uint32_t* __restrict__ hist, int* __restrict__ tbin) {
  __shared__ uint32_t s[256];
  __shared__ int fc;
  __shared__ uint32_t above;
  int t = threadIdx.x;

  uint32_t acc = 0;
  const uint4* h4 = (const uint4*)(hist + t * 256);
  for (int j = 0; j < 64; ++j) {
    uint4 v = h4[j];
    acc += v.x + v.y + v.z + v.w;
  }
  s[t] = acc;
  __syncthreads();
  // inclusive suffix sum over 256 chunk sums
  for (int off = 1; off < 256; off <<= 1) {
    uint32_t v = (t + off < 256) ? s[t + off] : 0u;
    __syncthreads();
    s[t] += v;
    __syncthreads();
  }
  if (s[t] >= TOPK && (t == 255 || s[t + 1] < TOPK)) {
    fc = t;
    above = (t == 255) ? 0u : s[t + 1];
  }
  __syncthreads();
  int c = fc;
  uint32_t a = above;
  uint32_t h = hist[c * 256 + t];
  __syncthreads();
  s[t] = h;
  __syncthreads();
  for (int off = 1; off < 256; off <<= 1) {
    uint32_t v = (t + off < 256) ? s[t + off] : 0u;
    __syncthreads();
    s[t] += v;
    __syncthreads();
  }
  if (a + s[t] >= TOPK && (t == 255 || a + s[t + 1] < TOPK)) {
    *tbin = c * 256 + t;
  }
}

// Kernel C: collect candidates with bin >= threshold.
// Packed key: (monotone score << 32) | ~idx  -> bigger = better, ties -> lower idx.
__global__ __launch_bounds__(256) void collect_kernel(
    const float* __restrict__ scores, const int* __restrict__ tbin,
    int* __restrict__ cnt, unsigned long long* __restrict__ cand, int n) {
  uint32_t T = (uint32_t)(*tbin);
  int i = blockIdx.x * 256 + threadIdx.x;
  int stride = gridDim.x * 256;
  for (; i < n; i += stride) {
    uint32_t key = fkey(scores[i]);
    if ((key >> 16) >= T) {
      int pos = atomicAdd(cnt, 1);
      if (pos < CAP) {
        cand[pos] = ((unsigned long long)key << 32) | (uint32_t)(~(uint32_t)i);
      }
    }
  }
}

// Kernel F: rank candidates (distinct keys -> exact ranks), emit idx (as f32)
// and gather the TOPK rows.
__global__ __launch_bounds__(256) void final_kernel(
    const unsigned long long* __restrict__ cand, const int* __restrict__ cnt,
    const float* __restrict__ mat, float* __restrict__ out) {
  __shared__ unsigned long long c[CAP];
  __shared__ int sel[TOPK];
  int t = threadIdx.x;
  int M = *cnt;
  if (M > CAP) M = CAP;

  for (int i = t; i < M; i += 256) c[i] = cand[i];
  __syncthreads();

  for (int i = t; i < M; i += 256) {
    unsigned long long mykey = c[i];
    int rank = 0;
    for (int j = 0; j < M; ++j) rank += (c[j] > mykey) ? 1 : 0;
    if (rank < TOPK) sel[rank] = (int)(~(uint32_t)(mykey & 0xFFFFFFFFull));
  }
  __syncthreads();

  // idx output, written as float32 values
  if (t < TOPK) out[TOPK * DIM + t] = (float)sel[t];

  // gather rows: wave w handles rows w, w+4, ... ; lane l copies float4 col block
  int wv = t >> 6, lane = t & 63;
  for (int r = wv; r < TOPK; r += 4) {
    size_t row = (size_t)sel[r];
    float4 v = ((const float4*)(mat + row * DIM))[lane];
    ((float4*)(out + r * DIM))[lane] = v;
  }
}

extern "C" void kernel_launch(void* const* d_in, const int* in_sizes, int n_in,
                              void* d_out, int out_size, void* d_ws, size_t ws_size,
                              hipStream_t stream) {
  const float* query = (const float*)d_in[0];
  const float* mat = (const float*)d_in[1];
  float* out = (float*)d_out;
  int n = in_sizes[1] / DIM;

  char* ws = (char*)d_ws;
  float* scores = (float*)ws;                               // n floats (<2 MB)
  uint32_t* hist = (uint32_t*)(ws + (2u << 20));            // 256 KB
  int* tbin = (int*)(ws + (2u << 20) + HIST_BINS * 4);
  int* cnt = tbin + 1;
  unsigned long long* cand =
      (unsigned long long*)(ws + (2u << 20) + HIST_BINS * 4 + 16);  // CAP*8

  int sblocks = (n + 3) / 4;  // 4 waves (rows) per 256-thread block
  score_kernel<<<sblocks, 256, 0, stream>>>(mat, query, scores, hist, cnt, n);
  hist_kernel<<<512, 256, 0, stream>>>(scores, hist, n);
  thresh_kernel<<<1, 256, 0, stream>>>(hist, tbin);
  collect_kernel<<<512, 256, 0, stream>>>(scores, tbin, cnt, cand, n);
  final_kernel<<<1, 256, 0, stream>>>(cand, cnt, mat, out);
}